// Round 4
// baseline (89.936 us; speedup 1.0000x reference)
//
#include <hip/hip_runtime.h>

#define NN 100000
#define DIN 128
#define DOUT 64
#define NE 1600000

#define BSHIFT 8
#define BROWS 256            // rows per bucket
#define NBB 391              // ceil(100000/256)
#define CAP 4736             // slots/bucket; mean 4096, sigma 64 -> +10 sigma
#define EPB 4096             // edges per place-block
#define NBLK 391             // ceil(1600000/4096)

// ---------------- ws layout (bytes) ----------------
#define XWB_B  0u                            // ushort[NN*DOUT] = 12.8 MB
#define GCUR_B 12800000u                     // int[NBB] (padded to 8 KB)
#define BPAD_B (GCUR_B + 8192u)              // int2[NBB*CAP] = 14.8 MB
#define WS_NEED (BPAD_B + (unsigned)NBB * CAP * 8u)   // ~27.6 MB

typedef unsigned short u16;
typedef unsigned int u32;
typedef __attribute__((ext_vector_type(8))) short v8s;   // 8 bf16 = 4 VGPR
typedef __attribute__((ext_vector_type(4))) float v4f;   // MFMA acc

__device__ __forceinline__ float bf2f(u16 u) {
  return __uint_as_float(((u32)u) << 16);
}
__device__ __forceinline__ u16 f2bf(float f) {
  u32 x = __float_as_uint(f);
  u32 r = x + 0x7fffu + ((x >> 16) & 1u);
  return (u16)(r >> 16);
}

// ---------------------------------------------------------------------------
// GEMM v7 (validated, ~11 us, HBM-bound). Also zeroes gcur (replaces the
// hipMemsetAsync dispatch): stream order guarantees place4 sees zeros.
// ---------------------------------------------------------------------------
__global__ __launch_bounds__(256) void gemm_kernel(
    const float* __restrict__ x, const float* __restrict__ w,
    u16* __restrict__ xwb, int* __restrict__ gz) {
  if (gz != nullptr && threadIdx.x == 0 && blockIdx.x < NBB)
    gz[blockIdx.x] = 0;

  __shared__ u16 wlds[16 * 64 * 8];   // 16 KB
  const int t = threadIdx.x;
  const int lane = t & 63;
  const int wv = t >> 6;

  #pragma unroll
  for (int pi = 0; pi < 4; ++pi) {
    const int p = t * 4 + pi;
    const int f = p >> 6, lp = p & 63;
    const int kc = f >> 2, nc = f & 3;
    const int kg = lp >> 4, lr = lp & 15;
    const int kbase = kc * 32 + kg * 8;
    u32 pk[4];
    #pragma unroll
    for (int h = 0; h < 4; ++h) {
      const u32 lo = f2bf(w[(kbase + 2 * h)     * DOUT + nc * 16 + lr]);
      const u32 hi = f2bf(w[(kbase + 2 * h + 1) * DOUT + nc * 16 + lr]);
      pk[h] = lo | (hi << 16);
    }
    *reinterpret_cast<uint4*>(&wlds[p * 8]) =
        make_uint4(pk[0], pk[1], pk[2], pk[3]);
  }
  __syncthreads();

  const int row0 = blockIdx.x * 64 + wv * 16;
  if (row0 >= NN) return;            // safe: after the only barrier
  const int lrow = lane & 15;
  const int lkg  = lane >> 4;

  v8s Bf[4][4];
  #pragma unroll
  for (int kc = 0; kc < 4; ++kc)
    #pragma unroll
    for (int nc = 0; nc < 4; ++nc)
      Bf[kc][nc] = *reinterpret_cast<const v8s*>(
          &wlds[((kc * 4 + nc) * 64 + lane) * 8]);

  const float* xr = x + (size_t)(row0 + lrow) * DIN + lkg * 8;
  float4 xa[4][2];
  #pragma unroll
  for (int kc = 0; kc < 4; ++kc) {
    xa[kc][0] = *reinterpret_cast<const float4*>(xr + kc * 32);
    xa[kc][1] = *reinterpret_cast<const float4*>(xr + kc * 32 + 4);
  }

  v4f acc[4];
  #pragma unroll
  for (int nc = 0; nc < 4; ++nc) acc[nc] = (v4f){0.f, 0.f, 0.f, 0.f};

  #pragma unroll
  for (int kc = 0; kc < 4; ++kc) {
    v8s Af;
    Af[0] = (short)f2bf(xa[kc][0].x);
    Af[1] = (short)f2bf(xa[kc][0].y);
    Af[2] = (short)f2bf(xa[kc][0].z);
    Af[3] = (short)f2bf(xa[kc][0].w);
    Af[4] = (short)f2bf(xa[kc][1].x);
    Af[5] = (short)f2bf(xa[kc][1].y);
    Af[6] = (short)f2bf(xa[kc][1].z);
    Af[7] = (short)f2bf(xa[kc][1].w);
    #pragma unroll
    for (int nc = 0; nc < 4; ++nc)
      acc[nc] = __builtin_amdgcn_mfma_f32_16x16x32_bf16(Af, Bf[kc][nc],
                                                        acc[nc], 0, 0, 0);
  }

  #pragma unroll
  for (int nc = 0; nc < 4; ++nc)
    #pragma unroll
    for (int j = 0; j < 4; ++j)
      xwb[(size_t)(row0 + lkg * 4 + j) * DOUT + nc * 16 + lrow] =
          f2bf(acc[nc][j]);
}

// ---------------------------------------------------------------------------
// place4 (round-17): block-local counting sort into LDS, run-contiguous
// bpad writes. 391 buckets x 256 rows -> runs of ~10.5 edges (84 B).
// EPB=4096 / 512 threads / 48 KB LDS -> 3 blocks/CU, 391 blocks: per-block
// critical path halves AND co-resident blocks hide each other's latency
// (round-3 failure: 109 KB LDS -> 1 block/CU, wall = single-block latency).
// Phase A caches erow/ecol/eval in regs (24 independent cold loads, full
// MLP); phase C is pure LDS.
// ---------------------------------------------------------------------------
__global__ __launch_bounds__(512) void place4_kernel(
    const int* __restrict__ erow, const int* __restrict__ ecol,
    const float* __restrict__ eval_, int* __restrict__ gcur,
    int2* __restrict__ bpad) {
  __shared__ int  hist[512];       // 2 KB (zeros beyond NBB)
  __shared__ int  lofs[512];       // 2 KB
  __shared__ int  lcur[512];       // 2 KB
  __shared__ int  base_[512];      // 2 KB
  __shared__ int  wtot[8];
  __shared__ u16  sb[EPB];         // 8 KB   bucket id per sorted pos
  __shared__ int2 dstl[EPB];       // 32 KB  payload per sorted pos

  const int t = threadIdx.x;
  const int lane = t & 63;
  const int wv = t >> 6;
  const int e0 = blockIdx.x * EPB;
  const int e1 = min(e0 + EPB, NE);
  const int ecount = e1 - e0;

  hist[t] = 0;
  lcur[t] = 0;
  __syncthreads();

  // A: histogram; cache all edge data in registers (independent loads)
  int er[8], ec[8];
  float ev[8];
  #pragma unroll
  for (int k = 0; k < 8; ++k) {
    const int e = e0 + t + k * 512;
    if (e < e1) {
      er[k] = erow[e];
      ec[k] = ecol[e];
      ev[k] = eval_[e];
      atomicAdd(&hist[er[k] >> BSHIFT], 1);
    } else {
      er[k] = -1;
    }
  }
  __syncthreads();

  // B: exclusive scan over 512 entries (1/thread, 8-wave shfl + wave offsets)
  const int h = hist[t];
  int s = h;
  #pragma unroll
  for (int o = 1; o < 64; o <<= 1) {
    const int u = __shfl_up(s, o);
    if (lane >= o) s += u;
  }
  if (lane == 63) wtot[wv] = s;
  __syncthreads();
  int woff = 0;
  #pragma unroll
  for (int w = 0; w < 8; ++w) woff += (w < wv) ? wtot[w] : 0;
  lofs[t] = woff + s - h;
  base_[t] = (h && t < NBB) ? atomicAdd(&gcur[t], h) : 0;
  __syncthreads();

  // C: rank + scatter payload into LDS sorted order (pure LDS)
  #pragma unroll
  for (int k = 0; k < 8; ++k) {
    if (er[k] >= 0) {
      const int b = er[k] >> BSHIFT;
      const int pos = lofs[b] + atomicAdd(&lcur[b], 1);
      dstl[pos] = make_int2(((er[k] & (BROWS - 1)) << 17) | ec[k],
                            __float_as_int(ev[k]));
      sb[pos] = (u16)b;
    }
  }
  __syncthreads();

  // D: stream sorted payload to bpad (runs of ~10.5 edges = contiguous)
  for (int p = t; p < ecount; p += 512) {
    const int b = sb[p];
    const int rk = base_[b] + (p - lofs[b]);
    if (rk < CAP) bpad[(long)b * CAP + rk] = dstl[p];
  }
}

// ---------------------------------------------------------------------------
// agg5: validated slot-vectorized aggregation adapted to 256-row buckets.
// One block (512 thr) per bucket: hist -> 256-entry scan (4/thread over one
// wave) -> counting sort into LDS -> wave = 4 slots x 16 lanes, each quartet
// step does 4 edges with ONE dwordx2 gather per lane, unroll x2, val=0 tail
// masking, cross-slot shfl_xor reduce, float4 store. bpad read twice
// (2nd pass L2-hit) to keep VGPRs low.
// ---------------------------------------------------------------------------
__global__ __launch_bounds__(512) void agg5_kernel(
    const int* __restrict__ gcur, const int2* __restrict__ bpad,
    const u16* __restrict__ xwb, float* __restrict__ out) {
  __shared__ int2 dst[CAP];        // 37.9 KB
  __shared__ int  hist[BROWS];
  __shared__ int  lptr[BROWS + 1];
  __shared__ int  cur[BROWS];

  const int bucket = blockIdx.x;
  const int t = threadIdx.x;
  const int count = min(gcur[bucket], CAP);
  const long sbase = (long)bucket * CAP;

  if (t < BROWS) hist[t] = 0;
  __syncthreads();

  for (int e = t; e < count; e += 512)
    atomicAdd(&hist[(bpad[sbase + e].x >> 17) & (BROWS - 1)], 1);
  __syncthreads();

  if (t < 64) {
    const int h0 = hist[4 * t],     h1 = hist[4 * t + 1];
    const int h2 = hist[4 * t + 2], h3 = hist[4 * t + 3];
    const int ps = h0 + h1 + h2 + h3;
    int s = ps;
    #pragma unroll
    for (int o = 1; o < 64; o <<= 1) {
      const int u = __shfl_up(s, o);
      if (t >= o) s += u;
    }
    const int excl = s - ps;
    lptr[4 * t]     = excl;                cur[4 * t]     = excl;
    lptr[4 * t + 1] = excl + h0;           cur[4 * t + 1] = excl + h0;
    lptr[4 * t + 2] = excl + h0 + h1;      cur[4 * t + 2] = excl + h0 + h1;
    lptr[4 * t + 3] = excl + h0 + h1 + h2; cur[4 * t + 3] = excl + h0 + h1 + h2;
    if (t == 63) lptr[BROWS] = s;
  }
  __syncthreads();

  for (int e = t; e < count; e += 512) {
    const int2 q = bpad[sbase + e];
    const int r = (q.x >> 17) & (BROWS - 1);
    const int pos = atomicAdd(&cur[r], 1);
    dst[pos] = q;
  }
  __syncthreads();

  const int lane = t & 63;
  const int wave = t >> 6;         // 0..7
  const int slot = lane >> 4;      // 0..3  (edge sub-slot)
  const int li   = lane & 15;      // 0..15 (covers 4 cols each via dwordx2)
  const int row0 = bucket << BSHIFT;
  const int cmax = count - 1;

  for (int r = wave; r < BROWS; r += 8) {
    const int row = row0 + r;
    if (row >= NN) break;
    const int s = lptr[r], en = lptr[r + 1];
    float a0 = 0.f, a1 = 0.f, a2 = 0.f, a3 = 0.f;
    for (int e = s; e < en; e += 8) {
      {
        const int idx = e + slot;
        const int2 q = dst[min(idx, cmax)];
        const float v = (idx < en) ? __int_as_float(q.y) : 0.f;
        const u32 col = (u32)q.x & 0x1FFFFu;
        const uint2 g = *reinterpret_cast<const uint2*>(
            xwb + (size_t)col * DOUT + li * 4);
        a0 = fmaf(v, __uint_as_float(g.x << 16), a0);
        a1 = fmaf(v, __uint_as_float(g.x & 0xFFFF0000u), a1);
        a2 = fmaf(v, __uint_as_float(g.y << 16), a2);
        a3 = fmaf(v, __uint_as_float(g.y & 0xFFFF0000u), a3);
      }
      {
        const int idx = e + 4 + slot;
        const int2 q = dst[min(idx, cmax)];
        const float v = (idx < en) ? __int_as_float(q.y) : 0.f;
        const u32 col = (u32)q.x & 0x1FFFFu;
        const uint2 g = *reinterpret_cast<const uint2*>(
            xwb + (size_t)col * DOUT + li * 4);
        a0 = fmaf(v, __uint_as_float(g.x << 16), a0);
        a1 = fmaf(v, __uint_as_float(g.x & 0xFFFF0000u), a1);
        a2 = fmaf(v, __uint_as_float(g.y << 16), a2);
        a3 = fmaf(v, __uint_as_float(g.y & 0xFFFF0000u), a3);
      }
    }
    // cross-slot reduce: all 4 slot copies of li end up holding the sum
    a0 += __shfl_xor(a0, 16); a0 += __shfl_xor(a0, 32);
    a1 += __shfl_xor(a1, 16); a1 += __shfl_xor(a1, 32);
    a2 += __shfl_xor(a2, 16); a2 += __shfl_xor(a2, 32);
    a3 += __shfl_xor(a3, 16); a3 += __shfl_xor(a3, 32);
    if (slot == 0) {
      float4 o;
      o.x = fmaxf(a0, 0.f); o.y = fmaxf(a1, 0.f);
      o.z = fmaxf(a2, 0.f); o.w = fmaxf(a3, 0.f);
      *reinterpret_cast<float4*>(&out[(size_t)row * DOUT + li * 4]) = o;
    }
  }
}

// ----------------------- fallback (atomic) path ----------------------------
__global__ __launch_bounds__(256) void scatter_kernel(
    const int* __restrict__ erow, const int* __restrict__ ecol,
    const float* __restrict__ eval_, const u16* __restrict__ xwb,
    float* __restrict__ out) {
  const int wave = (blockIdx.x * blockDim.x + threadIdx.x) >> 6;
  const int lane = threadIdx.x & 63;
  const int nwaves = (gridDim.x * blockDim.x) >> 6;
  const int per = (NE + nwaves - 1) / nwaves;
  const int e0 = wave * per;
  const int e1 = min(e0 + per, NE);
  for (int base = e0; base < e1; base += 64) {
    const int e = base + lane;
    int r = 0, c = 0; float v = 0.f;
    if (e < e1) { r = erow[e]; c = ecol[e]; v = eval_[e]; }
    const int cnt = min(64, e1 - base);
    for (int j = 0; j < cnt; ++j) {
      const int rj = __shfl(r, j);
      const int cj = __shfl(c, j);
      const float vj = __shfl(v, j);
      atomicAdd(&out[rj * DOUT + lane], vj * bf2f(xwb[cj * DOUT + lane]));
    }
  }
}

__global__ __launch_bounds__(256) void finish_kernel(float* __restrict__ out) {
  const int idx = (blockIdx.x * blockDim.x + threadIdx.x) * 4;
  if (idx < NN * DOUT) {
    float4 a = *reinterpret_cast<const float4*>(&out[idx]);
    a.x = fmaxf(a.x, 0.f); a.y = fmaxf(a.y, 0.f);
    a.z = fmaxf(a.z, 0.f); a.w = fmaxf(a.w, 0.f);
    *reinterpret_cast<float4*>(&out[idx]) = a;
  }
}

extern "C" void kernel_launch(void* const* d_in, const int* in_sizes, int n_in,
                              void* d_out, int out_size, void* d_ws, size_t ws_size,
                              hipStream_t stream) {
  const float* x     = (const float*)d_in[0];
  const int*   erow  = (const int*)d_in[1];
  const int*   ecol  = (const int*)d_in[2];
  const float* eval_ = (const float*)d_in[3];
  const float* w     = (const float*)d_in[4];
  float* out = (float*)d_out;

  char* ws = (char*)d_ws;
  u16* xwb = (u16*)(ws + XWB_B);
  const bool big_ws = (ws_size >= (size_t)WS_NEED);
  int* gcur = big_ws ? (int*)(ws + GCUR_B) : nullptr;

  const int gemm_grid = (NN + 63) / 64;   // 1563 blocks x 4 waves x 16 rows
  gemm_kernel<<<gemm_grid, 256, 0, stream>>>(x, w, xwb, gcur);

  if (big_ws) {
    int2* bpad = (int2*)(ws + BPAD_B);
    place4_kernel<<<NBLK, 512, 0, stream>>>(erow, ecol, eval_, gcur, bpad);
    agg5_kernel<<<NBB, 512, 0, stream>>>(gcur, bpad, xwb, out);
  } else {
    hipMemsetAsync(d_out, 0, (size_t)NN * DOUT * sizeof(float), stream);
    scatter_kernel<<<2048, 256, 0, stream>>>(erow, ecol, eval_, xwb, out);
    const int fin_grid = (NN * DOUT / 4 + 255) / 256;
    finish_kernel<<<fin_grid, 256, 0, stream>>>(out);
  }
}

// Round 5
// 79.520 us; speedup vs baseline: 1.1310x; 1.1310x over previous
//
#include <hip/hip_runtime.h>

#define NN 100000
#define DIN 128
#define DOUT 64
#define NE 1600000

#define BSHIFT 8
#define BROWS 256            // rows per bucket (place/bpad granularity)
#define NBB 391              // ceil(100000/256)
#define CAP 4736             // slots/bucket; mean 4096 -> +10 sigma
#define CAPQ 1536            // slots per 64-row quarter; mean 1024, +16 sigma
#define QRN 19               // ceil(CAP/256) register-cache depth
#define EPB 4096             // edges per place-block
#define NBLK 391             // ceil(1600000/4096)

// ---------------- ws layout (bytes) ----------------
#define XWB_B  0u                            // ushort[NN*DOUT] = 12.8 MB
#define GCUR_B 12800000u                     // int[NBB] (padded to 8 KB)
#define BPAD_B (GCUR_B + 8192u)              // int2[NBB*CAP] = 14.8 MB
#define WS_NEED (BPAD_B + (unsigned)NBB * CAP * 8u)   // ~27.6 MB

typedef unsigned short u16;
typedef unsigned int u32;
typedef __attribute__((ext_vector_type(8))) short v8s;   // 8 bf16 = 4 VGPR
typedef __attribute__((ext_vector_type(4))) float v4f;   // MFMA acc

__device__ __forceinline__ float bf2f(u16 u) {
  return __uint_as_float(((u32)u) << 16);
}
__device__ __forceinline__ u16 f2bf(float f) {
  u32 x = __float_as_uint(f);
  u32 r = x + 0x7fffu + ((x >> 16) & 1u);
  return (u16)(r >> 16);
}

// ---------------------------------------------------------------------------
// GEMM v7 (validated, ~11 us, HBM-bound). Also zeroes gcur (replaces the
// hipMemsetAsync dispatch): stream order guarantees place4 sees zeros.
// ---------------------------------------------------------------------------
__global__ __launch_bounds__(256) void gemm_kernel(
    const float* __restrict__ x, const float* __restrict__ w,
    u16* __restrict__ xwb, int* __restrict__ gz) {
  if (gz != nullptr && threadIdx.x == 0 && blockIdx.x < NBB)
    gz[blockIdx.x] = 0;

  __shared__ u16 wlds[16 * 64 * 8];   // 16 KB
  const int t = threadIdx.x;
  const int lane = t & 63;
  const int wv = t >> 6;

  #pragma unroll
  for (int pi = 0; pi < 4; ++pi) {
    const int p = t * 4 + pi;
    const int f = p >> 6, lp = p & 63;
    const int kc = f >> 2, nc = f & 3;
    const int kg = lp >> 4, lr = lp & 15;
    const int kbase = kc * 32 + kg * 8;
    u32 pk[4];
    #pragma unroll
    for (int h = 0; h < 4; ++h) {
      const u32 lo = f2bf(w[(kbase + 2 * h)     * DOUT + nc * 16 + lr]);
      const u32 hi = f2bf(w[(kbase + 2 * h + 1) * DOUT + nc * 16 + lr]);
      pk[h] = lo | (hi << 16);
    }
    *reinterpret_cast<uint4*>(&wlds[p * 8]) =
        make_uint4(pk[0], pk[1], pk[2], pk[3]);
  }
  __syncthreads();

  const int row0 = blockIdx.x * 64 + wv * 16;
  if (row0 >= NN) return;            // safe: after the only barrier
  const int lrow = lane & 15;
  const int lkg  = lane >> 4;

  v8s Bf[4][4];
  #pragma unroll
  for (int kc = 0; kc < 4; ++kc)
    #pragma unroll
    for (int nc = 0; nc < 4; ++nc)
      Bf[kc][nc] = *reinterpret_cast<const v8s*>(
          &wlds[((kc * 4 + nc) * 64 + lane) * 8]);

  const float* xr = x + (size_t)(row0 + lrow) * DIN + lkg * 8;
  float4 xa[4][2];
  #pragma unroll
  for (int kc = 0; kc < 4; ++kc) {
    xa[kc][0] = *reinterpret_cast<const float4*>(xr + kc * 32);
    xa[kc][1] = *reinterpret_cast<const float4*>(xr + kc * 32 + 4);
  }

  v4f acc[4];
  #pragma unroll
  for (int nc = 0; nc < 4; ++nc) acc[nc] = (v4f){0.f, 0.f, 0.f, 0.f};

  #pragma unroll
  for (int kc = 0; kc < 4; ++kc) {
    v8s Af;
    Af[0] = (short)f2bf(xa[kc][0].x);
    Af[1] = (short)f2bf(xa[kc][0].y);
    Af[2] = (short)f2bf(xa[kc][0].z);
    Af[3] = (short)f2bf(xa[kc][0].w);
    Af[4] = (short)f2bf(xa[kc][1].x);
    Af[5] = (short)f2bf(xa[kc][1].y);
    Af[6] = (short)f2bf(xa[kc][1].z);
    Af[7] = (short)f2bf(xa[kc][1].w);
    #pragma unroll
    for (int nc = 0; nc < 4; ++nc)
      acc[nc] = __builtin_amdgcn_mfma_f32_16x16x32_bf16(Af, Bf[kc][nc],
                                                        acc[nc], 0, 0, 0);
  }

  #pragma unroll
  for (int nc = 0; nc < 4; ++nc)
    #pragma unroll
    for (int j = 0; j < 4; ++j)
      xwb[(size_t)(row0 + lkg * 4 + j) * DOUT + nc * 16 + lrow] =
          f2bf(acc[nc][j]);
}

// ---------------------------------------------------------------------------
// place4 (round-17, validated ~21 us): block-local counting sort into LDS,
// run-contiguous bpad writes. 391 buckets x 256 rows -> runs of ~10.5 edges.
// EPB=4096 / 512 threads / 48 KB LDS -> 3 blocks/CU.
// ---------------------------------------------------------------------------
__global__ __launch_bounds__(512) void place4_kernel(
    const int* __restrict__ erow, const int* __restrict__ ecol,
    const float* __restrict__ eval_, int* __restrict__ gcur,
    int2* __restrict__ bpad) {
  __shared__ int  hist[512];       // 2 KB (zeros beyond NBB)
  __shared__ int  lofs[512];       // 2 KB
  __shared__ int  lcur[512];       // 2 KB
  __shared__ int  base_[512];      // 2 KB
  __shared__ int  wtot[8];
  __shared__ u16  sb[EPB];         // 8 KB   bucket id per sorted pos
  __shared__ int2 dstl[EPB];       // 32 KB  payload per sorted pos

  const int t = threadIdx.x;
  const int lane = t & 63;
  const int wv = t >> 6;
  const int e0 = blockIdx.x * EPB;
  const int e1 = min(e0 + EPB, NE);
  const int ecount = e1 - e0;

  hist[t] = 0;
  lcur[t] = 0;
  __syncthreads();

  // A: histogram; cache all edge data in registers (independent loads)
  int er[8], ec[8];
  float ev[8];
  #pragma unroll
  for (int k = 0; k < 8; ++k) {
    const int e = e0 + t + k * 512;
    if (e < e1) {
      er[k] = erow[e];
      ec[k] = ecol[e];
      ev[k] = eval_[e];
      atomicAdd(&hist[er[k] >> BSHIFT], 1);
    } else {
      er[k] = -1;
    }
  }
  __syncthreads();

  // B: exclusive scan over 512 entries (1/thread, 8-wave shfl + wave offsets)
  const int h = hist[t];
  int s = h;
  #pragma unroll
  for (int o = 1; o < 64; o <<= 1) {
    const int u = __shfl_up(s, o);
    if (lane >= o) s += u;
  }
  if (lane == 63) wtot[wv] = s;
  __syncthreads();
  int woff = 0;
  #pragma unroll
  for (int w = 0; w < 8; ++w) woff += (w < wv) ? wtot[w] : 0;
  lofs[t] = woff + s - h;
  base_[t] = (h && t < NBB) ? atomicAdd(&gcur[t], h) : 0;
  __syncthreads();

  // C: rank + scatter payload into LDS sorted order (pure LDS)
  #pragma unroll
  for (int k = 0; k < 8; ++k) {
    if (er[k] >= 0) {
      const int b = er[k] >> BSHIFT;
      const int pos = lofs[b] + atomicAdd(&lcur[b], 1);
      dstl[pos] = make_int2(((er[k] & (BROWS - 1)) << 17) | ec[k],
                            __float_as_int(ev[k]));
      sb[pos] = (u16)b;
    }
  }
  __syncthreads();

  // D: stream sorted payload to bpad (runs of ~10.5 edges = contiguous)
  for (int p = t; p < ecount; p += 512) {
    const int b = sb[p];
    const int rk = base_[b] + (p - lofs[b]);
    if (rk < CAP) bpad[(long)b * CAP + rk] = dstl[p];
  }
}

// ---------------------------------------------------------------------------
// agg6 (round-18): restore the PROVEN agg2 work quantum (256 thr / 64 rows /
// 4 waves / CAPQ=1536) on top of the 256-row bpad layout: 4 sub-blocks per
// bucket (grid 1564 -> 6.1 blocks/CU, fixes agg5's 391-block imbalance that
// cost 2x). Each sub-block streams the bucket segment ONCE into 19 reg int2
// (coalesced, L3-resident; 4x read amplification ~+44 MB accepted), filters
// rows to its quarter (bits 23-24), then hist/scan/sort + the validated
// slot-vectorized gather loop verbatim.
// ---------------------------------------------------------------------------
__global__ __launch_bounds__(256) void agg6_kernel(
    const int* __restrict__ gcur, const int2* __restrict__ bpad,
    const u16* __restrict__ xwb, float* __restrict__ out) {
  __shared__ int2 dst[CAPQ];       // 12288 B
  __shared__ int  hist[64];
  __shared__ int  lptr[65];
  __shared__ int  cur[64];

  const int bucket  = blockIdx.x >> 2;
  const int quarter = blockIdx.x & 3;
  const int t = threadIdx.x;
  const int count = min(gcur[bucket], CAP);
  const long sbase = (long)bucket * CAP;

  if (t < 64) hist[t] = 0;
  __syncthreads();

  // single streaming read of the bucket segment; keep only our quarter
  int2 qr[QRN];
  #pragma unroll
  for (int k = 0; k < QRN; ++k) {
    const int e = t + k * 256;
    qr[k].x = -1;
    if (e < count) {
      const int2 q = bpad[sbase + e];
      const int rr = (q.x >> 17) & (BROWS - 1);
      if ((rr >> 6) == quarter) {
        qr[k] = q;
        atomicAdd(&hist[rr & 63], 1);
      }
    }
  }
  __syncthreads();

  if (t < 64) {
    const int v = hist[t];
    int s = v;
    #pragma unroll
    for (int o = 1; o < 64; o <<= 1) {
      const int u = __shfl_up(s, o);
      if (t >= o) s += u;
    }
    lptr[t + 1] = min(s, CAPQ);
    cur[t] = s - v;
    if (t == 0) lptr[0] = 0;
  }
  __syncthreads();

  #pragma unroll
  for (int k = 0; k < QRN; ++k) {
    if (qr[k].x >= 0) {
      const int r = (qr[k].x >> 17) & 63;
      const int pos = atomicAdd(&cur[r], 1);
      if (pos < CAPQ) dst[pos] = qr[k];
    }
  }
  __syncthreads();

  const int lane = t & 63;
  const int wave = t >> 6;
  const int slot = lane >> 4;      // 0..3  (edge sub-slot)
  const int li   = lane & 15;      // 0..15 (covers 4 cols each via dwordx2)
  const int row0 = (bucket << BSHIFT) + (quarter << 6);
  const int kcount = lptr[64];
  const int cmax = kcount - 1;

  for (int r = wave; r < 64; r += 4) {
    const int row = row0 + r;
    if (row >= NN) break;
    const int s = lptr[r], en = lptr[r + 1];
    float a0 = 0.f, a1 = 0.f, a2 = 0.f, a3 = 0.f;
    for (int e = s; e < en; e += 8) {
      {
        const int idx = e + slot;
        const int2 q = dst[min(idx, cmax)];
        const float v = (idx < en) ? __int_as_float(q.y) : 0.f;
        const u32 col = (u32)q.x & 0x1FFFFu;
        const uint2 g = *reinterpret_cast<const uint2*>(
            xwb + (size_t)col * DOUT + li * 4);
        a0 = fmaf(v, __uint_as_float(g.x << 16), a0);
        a1 = fmaf(v, __uint_as_float(g.x & 0xFFFF0000u), a1);
        a2 = fmaf(v, __uint_as_float(g.y << 16), a2);
        a3 = fmaf(v, __uint_as_float(g.y & 0xFFFF0000u), a3);
      }
      {
        const int idx = e + 4 + slot;
        const int2 q = dst[min(idx, cmax)];
        const float v = (idx < en) ? __int_as_float(q.y) : 0.f;
        const u32 col = (u32)q.x & 0x1FFFFu;
        const uint2 g = *reinterpret_cast<const uint2*>(
            xwb + (size_t)col * DOUT + li * 4);
        a0 = fmaf(v, __uint_as_float(g.x << 16), a0);
        a1 = fmaf(v, __uint_as_float(g.x & 0xFFFF0000u), a1);
        a2 = fmaf(v, __uint_as_float(g.y << 16), a2);
        a3 = fmaf(v, __uint_as_float(g.y & 0xFFFF0000u), a3);
      }
    }
    // cross-slot reduce: all 4 slot copies of li end up holding the sum
    a0 += __shfl_xor(a0, 16); a0 += __shfl_xor(a0, 32);
    a1 += __shfl_xor(a1, 16); a1 += __shfl_xor(a1, 32);
    a2 += __shfl_xor(a2, 16); a2 += __shfl_xor(a2, 32);
    a3 += __shfl_xor(a3, 16); a3 += __shfl_xor(a3, 32);
    if (slot == 0) {
      float4 o;
      o.x = fmaxf(a0, 0.f); o.y = fmaxf(a1, 0.f);
      o.z = fmaxf(a2, 0.f); o.w = fmaxf(a3, 0.f);
      *reinterpret_cast<float4*>(&out[(size_t)row * DOUT + li * 4]) = o;
    }
  }
}

// ----------------------- fallback (atomic) path ----------------------------
__global__ __launch_bounds__(256) void scatter_kernel(
    const int* __restrict__ erow, const int* __restrict__ ecol,
    const float* __restrict__ eval_, const u16* __restrict__ xwb,
    float* __restrict__ out) {
  const int wave = (blockIdx.x * blockDim.x + threadIdx.x) >> 6;
  const int lane = threadIdx.x & 63;
  const int nwaves = (gridDim.x * blockDim.x) >> 6;
  const int per = (NE + nwaves - 1) / nwaves;
  const int e0 = wave * per;
  const int e1 = min(e0 + per, NE);
  for (int base = e0; base < e1; base += 64) {
    const int e = base + lane;
    int r = 0, c = 0; float v = 0.f;
    if (e < e1) { r = erow[e]; c = ecol[e]; v = eval_[e]; }
    const int cnt = min(64, e1 - base);
    for (int j = 0; j < cnt; ++j) {
      const int rj = __shfl(r, j);
      const int cj = __shfl(c, j);
      const float vj = __shfl(v, j);
      atomicAdd(&out[rj * DOUT + lane], vj * bf2f(xwb[cj * DOUT + lane]));
    }
  }
}

__global__ __launch_bounds__(256) void finish_kernel(float* __restrict__ out) {
  const int idx = (blockIdx.x * blockDim.x + threadIdx.x) * 4;
  if (idx < NN * DOUT) {
    float4 a = *reinterpret_cast<const float4*>(&out[idx]);
    a.x = fmaxf(a.x, 0.f); a.y = fmaxf(a.y, 0.f);
    a.z = fmaxf(a.z, 0.f); a.w = fmaxf(a.w, 0.f);
    *reinterpret_cast<float4*>(&out[idx]) = a;
  }
}

extern "C" void kernel_launch(void* const* d_in, const int* in_sizes, int n_in,
                              void* d_out, int out_size, void* d_ws, size_t ws_size,
                              hipStream_t stream) {
  const float* x     = (const float*)d_in[0];
  const int*   erow  = (const int*)d_in[1];
  const int*   ecol  = (const int*)d_in[2];
  const float* eval_ = (const float*)d_in[3];
  const float* w     = (const float*)d_in[4];
  float* out = (float*)d_out;

  char* ws = (char*)d_ws;
  u16* xwb = (u16*)(ws + XWB_B);
  const bool big_ws = (ws_size >= (size_t)WS_NEED);
  int* gcur = big_ws ? (int*)(ws + GCUR_B) : nullptr;

  const int gemm_grid = (NN + 63) / 64;   // 1563 blocks x 4 waves x 16 rows
  gemm_kernel<<<gemm_grid, 256, 0, stream>>>(x, w, xwb, gcur);

  if (big_ws) {
    int2* bpad = (int2*)(ws + BPAD_B);
    place4_kernel<<<NBLK, 512, 0, stream>>>(erow, ecol, eval_, gcur, bpad);
    agg6_kernel<<<NBB * 4, 256, 0, stream>>>(gcur, bpad, xwb, out);
  } else {
    hipMemsetAsync(d_out, 0, (size_t)NN * DOUT * sizeof(float), stream);
    scatter_kernel<<<2048, 256, 0, stream>>>(erow, ecol, eval_, xwb, out);
    const int fin_grid = (NN * DOUT / 4 + 255) / 256;
    finish_kernel<<<fin_grid, 256, 0, stream>>>(out);
  }
}

// Round 6
// 71.889 us; speedup vs baseline: 1.2511x; 1.1062x over previous
//
#include <hip/hip_runtime.h>

#define NN 100000
#define DIN 128
#define DOUT 64
#define NE 1600000

#define BSHIFT 7
#define BROWS 128            // rows per bucket
#define NBB 783              // ceil(100000/128)
#define NBP 1024             // padded key count for place scan
#define CAP 2560             // slots/bucket; mean 2048, sigma ~45 -> +11 sigma
#define QRN 5                // CAP / 512 register-cache depth (exact)
#define EPB 4096             // edges per place-block
#define NBLK 391             // ceil(1600000/4096)

// ---------------- ws layout (bytes) ----------------
#define XWB_B  0u                            // ushort[NN*DOUT] = 12.8 MB
#define GCUR_B 12800000u                     // int[NBB] (padded to 8 KB)
#define BPAD_B (GCUR_B + 8192u)              // int2[NBB*CAP] = 16.0 MB
#define WS_NEED (BPAD_B + (unsigned)NBB * CAP * 8u)   // ~28.8 MB

typedef unsigned short u16;
typedef unsigned int u32;
typedef __attribute__((ext_vector_type(8))) short v8s;   // 8 bf16 = 4 VGPR
typedef __attribute__((ext_vector_type(4))) float v4f;   // MFMA acc

__device__ __forceinline__ float bf2f(u16 u) {
  return __uint_as_float(((u32)u) << 16);
}
__device__ __forceinline__ u16 f2bf(float f) {
  u32 x = __float_as_uint(f);
  u32 r = x + 0x7fffu + ((x >> 16) & 1u);
  return (u16)(r >> 16);
}

// ---------------------------------------------------------------------------
// GEMM v7 (validated, ~11 us, HBM-bound). Also zeroes gcur (replaces the
// hipMemsetAsync dispatch): stream order guarantees place5 sees zeros.
// ---------------------------------------------------------------------------
__global__ __launch_bounds__(256) void gemm_kernel(
    const float* __restrict__ x, const float* __restrict__ w,
    u16* __restrict__ xwb, int* __restrict__ gz) {
  if (gz != nullptr && threadIdx.x == 0 && blockIdx.x < NBB)
    gz[blockIdx.x] = 0;

  __shared__ u16 wlds[16 * 64 * 8];   // 16 KB
  const int t = threadIdx.x;
  const int lane = t & 63;
  const int wv = t >> 6;

  #pragma unroll
  for (int pi = 0; pi < 4; ++pi) {
    const int p = t * 4 + pi;
    const int f = p >> 6, lp = p & 63;
    const int kc = f >> 2, nc = f & 3;
    const int kg = lp >> 4, lr = lp & 15;
    const int kbase = kc * 32 + kg * 8;
    u32 pk[4];
    #pragma unroll
    for (int h = 0; h < 4; ++h) {
      const u32 lo = f2bf(w[(kbase + 2 * h)     * DOUT + nc * 16 + lr]);
      const u32 hi = f2bf(w[(kbase + 2 * h + 1) * DOUT + nc * 16 + lr]);
      pk[h] = lo | (hi << 16);
    }
    *reinterpret_cast<uint4*>(&wlds[p * 8]) =
        make_uint4(pk[0], pk[1], pk[2], pk[3]);
  }
  __syncthreads();

  const int row0 = blockIdx.x * 64 + wv * 16;
  if (row0 >= NN) return;            // safe: after the only barrier
  const int lrow = lane & 15;
  const int lkg  = lane >> 4;

  v8s Bf[4][4];
  #pragma unroll
  for (int kc = 0; kc < 4; ++kc)
    #pragma unroll
    for (int nc = 0; nc < 4; ++nc)
      Bf[kc][nc] = *reinterpret_cast<const v8s*>(
          &wlds[((kc * 4 + nc) * 64 + lane) * 8]);

  const float* xr = x + (size_t)(row0 + lrow) * DIN + lkg * 8;
  float4 xa[4][2];
  #pragma unroll
  for (int kc = 0; kc < 4; ++kc) {
    xa[kc][0] = *reinterpret_cast<const float4*>(xr + kc * 32);
    xa[kc][1] = *reinterpret_cast<const float4*>(xr + kc * 32 + 4);
  }

  v4f acc[4];
  #pragma unroll
  for (int nc = 0; nc < 4; ++nc) acc[nc] = (v4f){0.f, 0.f, 0.f, 0.f};

  #pragma unroll
  for (int kc = 0; kc < 4; ++kc) {
    v8s Af;
    Af[0] = (short)f2bf(xa[kc][0].x);
    Af[1] = (short)f2bf(xa[kc][0].y);
    Af[2] = (short)f2bf(xa[kc][0].z);
    Af[3] = (short)f2bf(xa[kc][0].w);
    Af[4] = (short)f2bf(xa[kc][1].x);
    Af[5] = (short)f2bf(xa[kc][1].y);
    Af[6] = (short)f2bf(xa[kc][1].z);
    Af[7] = (short)f2bf(xa[kc][1].w);
    #pragma unroll
    for (int nc = 0; nc < 4; ++nc)
      acc[nc] = __builtin_amdgcn_mfma_f32_16x16x32_bf16(Af, Bf[kc][nc],
                                                        acc[nc], 0, 0, 0);
  }

  #pragma unroll
  for (int nc = 0; nc < 4; ++nc)
    #pragma unroll
    for (int j = 0; j < 4; ++j)
      xwb[(size_t)(row0 + lkg * 4 + j) * DOUT + nc * 16 + lrow] =
          f2bf(acc[nc][j]);
}

// ---------------------------------------------------------------------------
// place5 (round-19): place4 structure (EPB=4096 / 512 thr / reg-cached edge
// loads / LDS counting sort / run-contiguous bpad writes) with 128-row
// buckets: 784 sort keys, runs of ~5.2 edges (42 B, L2-mergeable).
// LDS ~53 KB -> 3 blocks/CU. Scan: pair-per-thread over 1024 padded keys.
// ---------------------------------------------------------------------------
__global__ __launch_bounds__(512) void place5_kernel(
    const int* __restrict__ erow, const int* __restrict__ ecol,
    const float* __restrict__ eval_, int* __restrict__ gcur,
    int2* __restrict__ bpad) {
  __shared__ int  hist[NBP];       // 4 KB (zeros beyond NBB)
  __shared__ int  lofs[NBP];       // 4 KB
  __shared__ int  lcur[NBP];       // 4 KB
  __shared__ int  base_[NBP];      // 4 KB
  __shared__ int  wtot[8];
  __shared__ u16  sb[EPB];         // 8 KB   bucket id per sorted pos
  __shared__ int2 dstl[EPB];       // 32 KB  payload per sorted pos

  const int t = threadIdx.x;
  const int lane = t & 63;
  const int wv = t >> 6;
  const int e0 = blockIdx.x * EPB;
  const int e1 = min(e0 + EPB, NE);
  const int ecount = e1 - e0;

  hist[t] = 0;        hist[t + 512] = 0;
  lcur[t] = 0;        lcur[t + 512] = 0;
  __syncthreads();

  // A: histogram; cache all edge data in registers (independent loads)
  int er[8], ec[8];
  float ev[8];
  #pragma unroll
  for (int k = 0; k < 8; ++k) {
    const int e = e0 + t + k * 512;
    if (e < e1) {
      er[k] = erow[e];
      ec[k] = ecol[e];
      ev[k] = eval_[e];
      atomicAdd(&hist[er[k] >> BSHIFT], 1);
    } else {
      er[k] = -1;
    }
  }
  __syncthreads();

  // B: exclusive scan over 1024 keys (pair-per-thread + wave shfl + offsets)
  const int ha = hist[2 * t], hb = hist[2 * t + 1];
  const int ps = ha + hb;
  int s = ps;
  #pragma unroll
  for (int o = 1; o < 64; o <<= 1) {
    const int u = __shfl_up(s, o);
    if (lane >= o) s += u;
  }
  if (lane == 63) wtot[wv] = s;
  __syncthreads();
  int woff = 0;
  #pragma unroll
  for (int w = 0; w < 8; ++w) woff += (w < wv) ? wtot[w] : 0;
  const int excl = woff + s - ps;
  lofs[2 * t]     = excl;
  lofs[2 * t + 1] = excl + ha;
  // claim bucket ranges (one global atomic per touched bucket)
  #pragma unroll
  for (int i = t; i < NBP; i += 512) {
    const int h = hist[i];
    base_[i] = (h && i < NBB) ? atomicAdd(&gcur[i], h) : 0;
  }
  __syncthreads();

  // C: rank + scatter payload into LDS sorted order (pure LDS)
  #pragma unroll
  for (int k = 0; k < 8; ++k) {
    if (er[k] >= 0) {
      const int b = er[k] >> BSHIFT;
      const int pos = lofs[b] + atomicAdd(&lcur[b], 1);
      dstl[pos] = make_int2(((er[k] & (BROWS - 1)) << 17) | ec[k],
                            __float_as_int(ev[k]));
      sb[pos] = (u16)b;
    }
  }
  __syncthreads();

  // D: stream sorted payload to bpad (runs of ~5.2 edges = contiguous)
  for (int p = t; p < ecount; p += 512) {
    const int b = sb[p];
    const int rk = base_[b] + (p - lofs[b]);
    if (rk < CAP) bpad[(long)b * CAP + rk] = dstl[p];
  }
}

// ---------------------------------------------------------------------------
// agg7 (round-19): one 512-thr block per 128-row bucket, grid 783
// (3.06 blocks/CU at 4-block residency -> fine-grained balance; fixes
// agg5's 391-block 2T wall) with ZERO read amplification (fixes agg6's
// 4x filter cost): segment reg-cached in exactly qr[5] (CAP=5*512),
// hist/scan/sort into LDS, then the validated slot-vectorized loop
// (16 rows/wave, dwordx2 gathers, val=0 tail masking, shfl_xor reduce).
// LDS ~21.6 KB, 24 VGPR.
// ---------------------------------------------------------------------------
__global__ __launch_bounds__(512) void agg7_kernel(
    const int* __restrict__ gcur, const int2* __restrict__ bpad,
    const u16* __restrict__ xwb, float* __restrict__ out) {
  __shared__ int2 dst[CAP];        // 20480 B
  __shared__ int  hist[BROWS];
  __shared__ int  lptr[BROWS + 1];
  __shared__ int  cur[BROWS];

  const int bucket = blockIdx.x;
  const int t = threadIdx.x;
  const int count = min(gcur[bucket], CAP);
  const long sbase = (long)bucket * CAP;

  if (t < BROWS) hist[t] = 0;
  __syncthreads();

  // single streaming read of this bucket's segment into registers
  int2 qr[QRN];
  #pragma unroll
  for (int k = 0; k < QRN; ++k) {
    const int e = t + k * 512;
    qr[k].x = -1;
    if (e < count) {
      qr[k] = bpad[sbase + e];
      atomicAdd(&hist[(qr[k].x >> 17) & (BROWS - 1)], 1);
    }
  }
  __syncthreads();

  // exclusive scan over 128 rows: pair-per-thread on one wave
  if (t < 64) {
    const int h0 = hist[2 * t], h1 = hist[2 * t + 1];
    const int ps = h0 + h1;
    int s = ps;
    #pragma unroll
    for (int o = 1; o < 64; o <<= 1) {
      const int u = __shfl_up(s, o);
      if (t >= o) s += u;
    }
    const int excl = s - ps;
    lptr[2 * t]     = excl;        cur[2 * t]     = excl;
    lptr[2 * t + 1] = excl + h0;   cur[2 * t + 1] = excl + h0;
    if (t == 63) lptr[BROWS] = s;
  }
  __syncthreads();

  #pragma unroll
  for (int k = 0; k < QRN; ++k) {
    if (qr[k].x >= 0) {
      const int r = (qr[k].x >> 17) & (BROWS - 1);
      const int pos = atomicAdd(&cur[r], 1);
      dst[pos] = qr[k];
    }
  }
  __syncthreads();

  const int lane = t & 63;
  const int wave = t >> 6;         // 0..7
  const int slot = lane >> 4;      // 0..3  (edge sub-slot)
  const int li   = lane & 15;      // 0..15 (covers 4 cols each via dwordx2)
  const int row0 = bucket << BSHIFT;
  const int cmax = count - 1;

  for (int r = wave; r < BROWS; r += 8) {
    const int row = row0 + r;
    if (row >= NN) break;
    const int s = lptr[r], en = lptr[r + 1];
    float a0 = 0.f, a1 = 0.f, a2 = 0.f, a3 = 0.f;
    for (int e = s; e < en; e += 8) {
      {
        const int idx = e + slot;
        const int2 q = dst[min(idx, cmax)];
        const float v = (idx < en) ? __int_as_float(q.y) : 0.f;
        const u32 col = (u32)q.x & 0x1FFFFu;
        const uint2 g = *reinterpret_cast<const uint2*>(
            xwb + (size_t)col * DOUT + li * 4);
        a0 = fmaf(v, __uint_as_float(g.x << 16), a0);
        a1 = fmaf(v, __uint_as_float(g.x & 0xFFFF0000u), a1);
        a2 = fmaf(v, __uint_as_float(g.y << 16), a2);
        a3 = fmaf(v, __uint_as_float(g.y & 0xFFFF0000u), a3);
      }
      {
        const int idx = e + 4 + slot;
        const int2 q = dst[min(idx, cmax)];
        const float v = (idx < en) ? __int_as_float(q.y) : 0.f;
        const u32 col = (u32)q.x & 0x1FFFFu;
        const uint2 g = *reinterpret_cast<const uint2*>(
            xwb + (size_t)col * DOUT + li * 4);
        a0 = fmaf(v, __uint_as_float(g.x << 16), a0);
        a1 = fmaf(v, __uint_as_float(g.x & 0xFFFF0000u), a1);
        a2 = fmaf(v, __uint_as_float(g.y << 16), a2);
        a3 = fmaf(v, __uint_as_float(g.y & 0xFFFF0000u), a3);
      }
    }
    // cross-slot reduce: all 4 slot copies of li end up holding the sum
    a0 += __shfl_xor(a0, 16); a0 += __shfl_xor(a0, 32);
    a1 += __shfl_xor(a1, 16); a1 += __shfl_xor(a1, 32);
    a2 += __shfl_xor(a2, 16); a2 += __shfl_xor(a2, 32);
    a3 += __shfl_xor(a3, 16); a3 += __shfl_xor(a3, 32);
    if (slot == 0) {
      float4 o;
      o.x = fmaxf(a0, 0.f); o.y = fmaxf(a1, 0.f);
      o.z = fmaxf(a2, 0.f); o.w = fmaxf(a3, 0.f);
      *reinterpret_cast<float4*>(&out[(size_t)row * DOUT + li * 4]) = o;
    }
  }
}

// ----------------------- fallback (atomic) path ----------------------------
__global__ __launch_bounds__(256) void scatter_kernel(
    const int* __restrict__ erow, const int* __restrict__ ecol,
    const float* __restrict__ eval_, const u16* __restrict__ xwb,
    float* __restrict__ out) {
  const int wave = (blockIdx.x * blockDim.x + threadIdx.x) >> 6;
  const int lane = threadIdx.x & 63;
  const int nwaves = (gridDim.x * blockDim.x) >> 6;
  const int per = (NE + nwaves - 1) / nwaves;
  const int e0 = wave * per;
  const int e1 = min(e0 + per, NE);
  for (int base = e0; base < e1; base += 64) {
    const int e = base + lane;
    int r = 0, c = 0; float v = 0.f;
    if (e < e1) { r = erow[e]; c = ecol[e]; v = eval_[e]; }
    const int cnt = min(64, e1 - base);
    for (int j = 0; j < cnt; ++j) {
      const int rj = __shfl(r, j);
      const int cj = __shfl(c, j);
      const float vj = __shfl(v, j);
      atomicAdd(&out[rj * DOUT + lane], vj * bf2f(xwb[cj * DOUT + lane]));
    }
  }
}

__global__ __launch_bounds__(256) void finish_kernel(float* __restrict__ out) {
  const int idx = (blockIdx.x * blockDim.x + threadIdx.x) * 4;
  if (idx < NN * DOUT) {
    float4 a = *reinterpret_cast<const float4*>(&out[idx]);
    a.x = fmaxf(a.x, 0.f); a.y = fmaxf(a.y, 0.f);
    a.z = fmaxf(a.z, 0.f); a.w = fmaxf(a.w, 0.f);
    *reinterpret_cast<float4*>(&out[idx]) = a;
  }
}

extern "C" void kernel_launch(void* const* d_in, const int* in_sizes, int n_in,
                              void* d_out, int out_size, void* d_ws, size_t ws_size,
                              hipStream_t stream) {
  const float* x     = (const float*)d_in[0];
  const int*   erow  = (const int*)d_in[1];
  const int*   ecol  = (const int*)d_in[2];
  const float* eval_ = (const float*)d_in[3];
  const float* w     = (const float*)d_in[4];
  float* out = (float*)d_out;

  char* ws = (char*)d_ws;
  u16* xwb = (u16*)(ws + XWB_B);
  const bool big_ws = (ws_size >= (size_t)WS_NEED);
  int* gcur = big_ws ? (int*)(ws + GCUR_B) : nullptr;

  const int gemm_grid = (NN + 63) / 64;   // 1563 blocks x 4 waves x 16 rows
  gemm_kernel<<<gemm_grid, 256, 0, stream>>>(x, w, xwb, gcur);

  if (big_ws) {
    int2* bpad = (int2*)(ws + BPAD_B);
    place5_kernel<<<NBLK, 512, 0, stream>>>(erow, ecol, eval_, gcur, bpad);
    agg7_kernel<<<NBB, 512, 0, stream>>>(gcur, bpad, xwb, out);
  } else {
    hipMemsetAsync(d_out, 0, (size_t)NN * DOUT * sizeof(float), stream);
    scatter_kernel<<<2048, 256, 0, stream>>>(erow, ecol, eval_, xwb, out);
    const int fin_grid = (NN * DOUT / 4 + 255) / 256;
    finish_kernel<<<fin_grid, 256, 0, stream>>>(out);
  }
}